// Round 3
// baseline (468.553 us; speedup 1.0000x reference)
//
#include <hip/hip_runtime.h>

// BatchAdaptiveConv2d via implicit GEMM on bf16 MFMA.
// out[b,o,y,x] = sum_{i,dy,dx} x[b,i,y+dy-1,x+dx-1] * W[i,o,dy,dx]*wadapt[b,i]
//               + bias[o]*badapt[b,o]
// R3: same 9-shifted-GEMM structure as R2, plus:
//  - wbuf/xbuf LDS union (wbuf dead after A-fragment hoist) -> 33.8 KB, 4 blk/CU
//  - register-prefetch pipeline: issue next-4-rows loads BEFORE compute,
//    pack+ds_write after the post-compute barrier (latency hidden)
//  - coalesced adapt_kernel (dwordx4 rows + wave butterfly reduce)

#define B_    16
#define CIN   32
#define COUT  32
#define H_    256
#define W_    256
#define EMB2  512

#define XPX       66            // 64 + 2 halo pixels per LDS row
#define PXS       32            // ushorts per pixel (32 ch * bf16)
#define ROWSZ     (XPX*PXS)     // 2112 ushorts per LDS row-slot
#define NSLOT     8

using short8  = __attribute__((ext_vector_type(8))) short;
using float4v = __attribute__((ext_vector_type(4))) float;

__device__ __forceinline__ unsigned short f2bf(float f) {
    unsigned u = __builtin_bit_cast(unsigned, f);
    u += 0x7FFFu + ((u >> 16) & 1u);      // RNE
    return (unsigned short)(u >> 16);
}
__device__ __forceinline__ unsigned pk2(float a, float b) {
    return (unsigned)f2bf(a) | ((unsigned)f2bf(b) << 16);
}

// ---------------- kernel 1: adapt coefficients ----------------
// ws[0..511] = wadapt[b][i]; ws[512..1023] = bias[o]*badapt[b][o]
__global__ __launch_bounds__(256) void adapt_kernel(
    const float* __restrict__ cond, const float* __restrict__ lpe,
    const float* __restrict__ wa_w, const float* __restrict__ wa_b,
    const float* __restrict__ ba_w, const float* __restrict__ ba_b,
    const float* __restrict__ bias, float* __restrict__ ws)
{
    const int b    = blockIdx.x;
    const int lane = threadIdx.x & 63;
    const int w    = threadIdx.x >> 6;

    // lane's slice of i = [cond|lpe]: elements lane*8 .. lane*8+7 (coalesced x4)
    float ivr[8];
    #pragma unroll
    for (int j = 0; j < 8; ++j) {
        int e = lane*8 + j;
        ivr[j] = (e < 256) ? cond[b*256 + e] : lpe[b*256 + e - 256];
    }

    for (int r = w; r < 64; r += 4) {               // 16 outputs per wave
        const float* row = (r < 32) ? (wa_w + r*EMB2) : (ba_w + (r-32)*EMB2);
        float s = 0.f;
        #pragma unroll
        for (int j = 0; j < 8; ++j) s += ivr[j] * row[lane*8 + j];
        #pragma unroll
        for (int off = 32; off; off >>= 1) s += __shfl_xor(s, off, 64);
        if (lane == 0) {
            if (r < 32) ws[b*32 + r] = s + wa_b[r];
            else {
                int o = r - 32;
                ws[512 + b*32 + o] = bias[o] * (s + ba_b[o]);
            }
        }
    }
}

// ---------------- kernel 2: MFMA conv ----------------
// grid (W/64, H/32, B); block 256 = 4 waves. Wave w -> output row 4t+w.
__global__ __launch_bounds__(256, 3) void conv_kernel(
    const float* __restrict__ x, const float* __restrict__ weights,
    const float* __restrict__ ws, float* __restrict__ out)
{
    // union: wbuf (9216 ushorts, phase 1 only) aliases xbuf (16896 ushorts)
    __shared__ unsigned short smem[NSLOT * ROWSZ];   // 33792 B
    unsigned short* wbuf = smem;
    unsigned short* xbuf = smem;

    const int tid    = threadIdx.x;
    const int lane   = tid & 63;
    const int w      = tid >> 6;
    const int ln15   = lane & 15;
    const int kg     = lane >> 4;
    const int xstrip = blockIdx.x * 64;
    const int ystrip = blockIdx.y * 32;
    const int b      = blockIdx.z;

    // ---- phase 1: scaled weights -> wbuf[tap*1024 + o*32 + i] ----
    for (int idx = tid; idx < CIN*COUT*9; idx += 256) {
        int i   = idx / 288;
        int rem = idx - i*288;
        int o   = rem / 9;
        int tap = rem - o*9;
        wbuf[tap*1024 + o*32 + i] = f2bf(weights[idx] * ws[b*32 + i]);
    }
    __syncthreads();

    // hoist A-fragments (m=out=ln15, k=kg*8+j)
    short8 wA[9][2];
    #pragma unroll
    for (int tap = 0; tap < 9; ++tap)
        #pragma unroll
        for (int ot = 0; ot < 2; ++ot)
            wA[tap][ot] = *(const short8*)&wbuf[tap*1024 + (ot*16 + ln15)*32 + kg*8];

    float bm[2][4];
    #pragma unroll
    for (int ot = 0; ot < 2; ++ot)
        #pragma unroll
        for (int r = 0; r < 4; ++r)
            bm[ot][r] = ws[512 + b*32 + ot*16 + kg*4 + r];
    __syncthreads();   // wbuf dead; smem is now xbuf

    // ---- staging helpers ----
    // item idx -> pixel p, channel-group g (8 ch), row offset rr
    auto issue_item = [&](int idx, int r0, float* pf) {
        int p  = idx % XPX;
        int t2 = idx / XPX;
        int g  = t2 & 3;
        int rr = t2 >> 2;
        int gy = ystrip + r0 + rr;
        int gx = xstrip + p - 1;
        int gyc = min(max(gy, 0), 255);
        int gxc = min(max(gx, 0), 255);
        const float* src = x + (((size_t)(b*CIN + g*8)) << 16) + (gyc << 8) + gxc;
        #pragma unroll
        for (int q = 0; q < 8; ++q) pf[q] = src[(size_t)q << 16];
    };
    auto pack_item = [&](int idx, int r0, const float* pf) {
        int p  = idx % XPX;
        int t2 = idx / XPX;
        int g  = t2 & 3;
        int rr = t2 >> 2;
        int gy = ystrip + r0 + rr;
        int gx = xstrip + p - 1;
        bool ok = ((unsigned)gy < 256u) & ((unsigned)gx < 256u);
        int slot = (r0 + rr + 1) & 7;
        unsigned dst = slot*ROWSZ + p*PXS + ((g ^ ((p >> 1) & 3)) * 8);
        uint4 v;
        if (ok) {
            v.x = pk2(pf[0], pf[1]); v.y = pk2(pf[2], pf[3]);
            v.z = pk2(pf[4], pf[5]); v.w = pk2(pf[6], pf[7]);
        } else v = uint4{0u,0u,0u,0u};
        *(uint4*)&xbuf[dst] = v;
    };

    // ---- prologue: rows -1..4 (two 3-row batches, loads batched ahead) ----
    #pragma unroll
    for (int hb = 0; hb < 2; ++hb) {
        const int r0 = -1 + hb*3;
        float pf[4][8];
        #pragma unroll
        for (int it = 0; it < 4; ++it) {
            int idx = tid + it*256;
            if (idx < 3*XPX*4) issue_item(idx, r0, pf[it]);
        }
        #pragma unroll
        for (int it = 0; it < 4; ++it) {
            int idx = tid + it*256;
            if (idx < 3*XPX*4) pack_item(idx, r0, pf[it]);
        }
    }
    __syncthreads();

    // ---- main loop: 8 iterations of 4 output rows ----
    for (int t = 0; t < 8; ++t) {
        // issue prefetch for rows 4t+5..4t+8 (consumed next iteration)
        float pf[5][8];
        const int pr0 = 4*t + 5;
        if (t < 7) {
            #pragma unroll
            for (int it = 0; it < 5; ++it) {
                int idx = tid + it*256;
                if (idx < 4*XPX*4) issue_item(idx, pr0, pf[it]);
            }
        }

        const int orow = 4*t + w;
        const int gy   = ystrip + orow;

        float4v acc[4][2];
        #pragma unroll
        for (int c = 0; c < 4; ++c) {
            acc[c][0] = float4v{0.f,0.f,0.f,0.f};
            acc[c][1] = float4v{0.f,0.f,0.f,0.f};
        }

        #pragma unroll
        for (int dy = 0; dy < 3; ++dy) {
            const int rowbase = ((orow + dy) & 7) * ROWSZ;
            #pragma unroll
            for (int dx = 0; dx < 3; ++dx) {
                const int tap = dy*3 + dx;
                #pragma unroll
                for (int c = 0; c < 4; ++c) {
                    int p = c*16 + dx + ln15;
                    int a = rowbase + p*PXS + ((kg ^ ((p >> 1) & 3)) * 8);
                    short8 xf = *(const short8*)&xbuf[a];
                    acc[c][0] = __builtin_amdgcn_mfma_f32_16x16x32_bf16(
                                    wA[tap][0], xf, acc[c][0], 0, 0, 0);
                    acc[c][1] = __builtin_amdgcn_mfma_f32_16x16x32_bf16(
                                    wA[tap][1], xf, acc[c][1], 0, 0, 0);
                }
            }
        }

        // store D (+modulated bias): row(out)=kg*4+r, col(pixel)=ln15
        #pragma unroll
        for (int c = 0; c < 4; ++c) {
            const int xcol = xstrip + c*16 + ln15;
            #pragma unroll
            for (int ot = 0; ot < 2; ++ot) {
                const int obase = ot*16 + kg*4;
                #pragma unroll
                for (int r = 0; r < 4; ++r) {
                    out[(((size_t)(b*COUT + obase + r) << 8) | (unsigned)gy) * 256
                        + xcol] = acc[c][ot][r] + bm[ot][r];
                }
            }
        }

        if (t < 7) {
            __syncthreads();          // all reads of old slots done
            #pragma unroll
            for (int it = 0; it < 5; ++it) {
                int idx = tid + it*256;
                if (idx < 4*XPX*4) pack_item(idx, pr0, pf[it]);
            }
            __syncthreads();          // new slots visible
        }
    }
}

extern "C" void kernel_launch(void* const* d_in, const int* in_sizes, int n_in,
                              void* d_out, int out_size, void* d_ws, size_t ws_size,
                              hipStream_t stream) {
    const float* x       = (const float*)d_in[0];
    const float* cond    = (const float*)d_in[1];
    const float* lpe     = (const float*)d_in[2];
    const float* weights = (const float*)d_in[3];
    const float* bias    = (const float*)d_in[4];
    const float* wa_w    = (const float*)d_in[5];
    const float* wa_b    = (const float*)d_in[6];
    const float* ba_w    = (const float*)d_in[7];
    const float* ba_b    = (const float*)d_in[8];
    float* outp = (float*)d_out;
    float* ws   = (float*)d_ws;    // 1024 floats: wadapt | bias*badapt

    adapt_kernel<<<dim3(B_), dim3(256), 0, stream>>>(
        cond, lpe, wa_w, wa_b, ba_w, ba_b, bias, ws);

    conv_kernel<<<dim3(W_/64, H_/32, B_), dim3(256), 0, stream>>>(
        x, weights, ws, outp);
}

// Round 4
// 287.498 us; speedup vs baseline: 1.6298x; 1.6298x over previous
//
#include <hip/hip_runtime.h>

// BatchAdaptiveConv2d via implicit GEMM on bf16 MFMA.
// out[b,o,y,x] = sum_{i,dy,dx} x[b,i,y+dy-1,x+dx-1] * W[i,o,dy,dx]*wadapt[b,i]
//               + bias[o]*badapt[b,o]
// R4: R2 structure + async global_load_lds staging (fp32) -> pack to bf16 ring.
//  - global->LDS is async, zero VGPR footprint (R3's register prefetch spilled:
//    WRITE_SIZE 131->346 MB was scratch traffic).
//  - end-of-iter __syncthreads drains vmcnt AFTER the compute phase -> the
//    900-cyc HBM latency is fully hidden.
//  - wbuf aliases the fp32 stage buffer; LDS 65 KB -> 2 blocks/CU (grid = 512
//    blocks = exactly 2/CU, single fully-resident round).

#define B_    16
#define CIN   32
#define COUT  32
#define H_    256
#define W_    256
#define EMB2  512

#define XPX   66                 // 64 + 2 halo pixels per ring row
#define PXS   32                 // ushorts per pixel (32 ch bf16)
#define ROWSZ (XPX*PXS)          // 2112 ushorts per ring slot
#define STG_ROW (CIN*64)         // 2048 floats per stage row-slot

using short8  = __attribute__((ext_vector_type(8))) short;
using float4v = __attribute__((ext_vector_type(4))) float;

__device__ __forceinline__ unsigned short f2bf(float f) {
    unsigned u = __builtin_bit_cast(unsigned, f);
    u += 0x7FFFu + ((u >> 16) & 1u);      // RNE
    return (unsigned short)(u >> 16);
}
__device__ __forceinline__ unsigned pk2(float a, float b) {
    return (unsigned)f2bf(a) | ((unsigned)f2bf(b) << 16);
}
__device__ __forceinline__ void async_cp16(const float* g, float* l) {
    __builtin_amdgcn_global_load_lds(
        (const __attribute__((address_space(1))) unsigned int*)g,
        (__attribute__((address_space(3))) unsigned int*)l, 16, 0, 0);
}

// ---------------- kernel 1: adapt coefficients ----------------
// ws[0..511] = wadapt[b][i]; ws[512..1023] = bias[o]*badapt[b][o]
__global__ __launch_bounds__(256) void adapt_kernel(
    const float* __restrict__ cond, const float* __restrict__ lpe,
    const float* __restrict__ wa_w, const float* __restrict__ wa_b,
    const float* __restrict__ ba_w, const float* __restrict__ ba_b,
    const float* __restrict__ bias, float* __restrict__ ws)
{
    const int b    = blockIdx.x;
    const int lane = threadIdx.x & 63;
    const int w    = threadIdx.x >> 6;

    float ivr[8];
    #pragma unroll
    for (int j = 0; j < 8; ++j) {
        int e = lane*8 + j;
        ivr[j] = (e < 256) ? cond[b*256 + e] : lpe[b*256 + e - 256];
    }
    for (int r = w; r < 64; r += 4) {
        const float* row = (r < 32) ? (wa_w + r*EMB2) : (ba_w + (r-32)*EMB2);
        float s = 0.f;
        #pragma unroll
        for (int j = 0; j < 8; ++j) s += ivr[j] * row[lane*8 + j];
        #pragma unroll
        for (int off = 32; off; off >>= 1) s += __shfl_xor(s, off, 64);
        if (lane == 0) {
            if (r < 32) ws[b*32 + r] = s + wa_b[r];
            else {
                int o = r - 32;
                ws[512 + b*32 + o] = bias[o] * (s + ba_b[o]);
            }
        }
    }
}

// ---------------- kernel 2: MFMA conv ----------------
// grid (W/64, H/32, B) = 512 blocks; block 256 = 4 waves.
// Wave w: stages/packs row 4t+1+w, computes output row 4t+w.
__global__ __launch_bounds__(256, 2) void conv_kernel(
    const float* __restrict__ x, const float* __restrict__ weights,
    const float* __restrict__ ws, float* __restrict__ out)
{
    __shared__ unsigned short ring[8 * ROWSZ];   // 33792 B bf16 ring
    __shared__ float stage[4 * STG_ROW];         // 32768 B fp32 async stage
    unsigned short* wbuf = (unsigned short*)stage;  // phase-1 alias (18432 B)

    const int tid    = threadIdx.x;
    const int lane   = tid & 63;
    const int w      = tid >> 6;
    const int ln15   = lane & 15;
    const int kg     = lane >> 4;
    const int xstrip = blockIdx.x * 64;
    const int ystrip = blockIdx.y * 32;
    const int b      = blockIdx.z;

    // ---- phase 1: scaled weights -> wbuf[tap*1024 + o*32 + i] ----
    for (int idx = tid; idx < CIN*COUT*9; idx += 256) {
        int i   = idx / 288;
        int rem = idx - i*288;
        int o   = rem / 9;
        int tap = rem - o*9;
        wbuf[tap*1024 + o*32 + i] = f2bf(weights[idx] * ws[b*32 + i]);
    }
    __syncthreads();

    short8 wA[9][2];
    #pragma unroll
    for (int tap = 0; tap < 9; ++tap)
        #pragma unroll
        for (int ot = 0; ot < 2; ++ot)
            wA[tap][ot] = *(const short8*)&wbuf[tap*1024 + (ot*16 + ln15)*32 + kg*8];

    float bm[2][4];
    #pragma unroll
    for (int ot = 0; ot < 2; ++ot)
        #pragma unroll
        for (int r = 0; r < 4; ++r)
            bm[ot][r] = ws[512 + b*32 + ot*16 + kg*4 + r];
    __syncthreads();   // wbuf dead; stage free for async

    // ---- staging helpers (one ROW per wave) ----
    auto issue_async_row = [&](int r) {           // interior 64 px, 32 ch, fp32
        int gyc = min(max(ystrip + r, 0), 255);
        const float* base = x + (((size_t)b*CIN) << 16) + ((size_t)gyc << 8) + xstrip;
        const int c  = lane >> 4;                 // 0..3 within inst
        const int px = (lane & 15) * 4;
        float* lds   = &stage[(r & 3) * STG_ROW];
        #pragma unroll
        for (int q = 0; q < 8; ++q)
            async_cp16(base + (((size_t)(q*4 + c)) << 16) + px, &lds[q * 256]);
    };
    auto load_halo = [&](int r) -> float {        // 1 value/thread: 2 px x 32 ch
        int side = lane >> 5;
        int ch   = lane & 31;
        int gyc  = min(max(ystrip + r, 0), 255);
        int gx   = side ? (xstrip + 64) : (xstrip - 1);
        int gxc  = min(max(gx, 0), 255);
        return x[(((size_t)(b*CIN + ch)) << 16) + (gyc << 8) + gxc];
    };
    auto pack_row = [&](int r, float hval) {      // stage(+halo reg) -> ring
        const bool rowok = ((unsigned)(ystrip + r) < 256u);
        unsigned short* rp = &ring[((r + 1) & 7) * ROWSZ];
        const float* st = &stage[(r & 3) * STG_ROW + lane];
        const int p = lane + 1;                   // interior pixel 1..64
        unsigned u[16];
        if (rowok) {
            #pragma unroll
            for (int h = 0; h < 16; ++h)
                u[h] = pk2(st[(2*h) * 64], st[(2*h + 1) * 64]);
        } else {
            #pragma unroll
            for (int h = 0; h < 16; ++h) u[h] = 0u;
        }
        #pragma unroll
        for (int g = 0; g < 4; ++g) {
            uint4 v{u[g*4+0], u[g*4+1], u[g*4+2], u[g*4+3]};
            *(uint4*)&rp[p*PXS + ((g ^ ((p >> 1) & 3)) * 8)] = v;
        }
        int side = lane >> 5;
        int ch   = lane & 31;
        int ph   = side ? 65 : 0;
        int gx   = side ? (xstrip + 64) : (xstrip - 1);
        bool ok  = rowok && ((unsigned)gx < 256u);
        rp[ph*PXS + (((ch >> 3) ^ ((ph >> 1) & 3)) * 8) + (ch & 7)] =
            ok ? f2bf(hval) : (unsigned short)0;
    };

    // ---- prologue: rows -1..0 (waves 0,1), then rows 1..4 (all waves) ----
    float hA = 0.f;
    if (w < 2) { hA = load_halo(w - 1); issue_async_row(w - 1); }
    __syncthreads();                    // drain round-A async
    if (w < 2) pack_row(w - 1, hA);
    __syncthreads();                    // round-A stage reads done
    float h_next = load_halo(1 + w);
    issue_async_row(1 + w);
    __syncthreads();                    // drain round-B async (rows 1..4 ready)

    // ---- main loop ----
    for (int t = 0; t < 8; ++t) {
        pack_row(4*t + 1 + w, h_next);
        __syncthreads();                // ring visible; stage reads done
        if (t < 7) {
            issue_async_row(4*t + 5 + w);
            h_next = load_halo(4*t + 5 + w);
        }

        const int orow = 4*t + w;
        const int gy   = ystrip + orow;

        float4v acc[4][2];
        #pragma unroll
        for (int c = 0; c < 4; ++c) {
            acc[c][0] = float4v{0.f,0.f,0.f,0.f};
            acc[c][1] = float4v{0.f,0.f,0.f,0.f};
        }
        #pragma unroll
        for (int dy = 0; dy < 3; ++dy) {
            const int rowbase = ((orow + dy) & 7) * ROWSZ;
            #pragma unroll
            for (int dx = 0; dx < 3; ++dx) {
                const int tap = dy*3 + dx;
                #pragma unroll
                for (int c = 0; c < 4; ++c) {
                    int p = c*16 + dx + ln15;
                    int a = rowbase + p*PXS + ((kg ^ ((p >> 1) & 3)) * 8);
                    short8 xf = *(const short8*)&ring[a];
                    acc[c][0] = __builtin_amdgcn_mfma_f32_16x16x32_bf16(
                                    wA[tap][0], xf, acc[c][0], 0, 0, 0);
                    acc[c][1] = __builtin_amdgcn_mfma_f32_16x16x32_bf16(
                                    wA[tap][1], xf, acc[c][1], 0, 0, 0);
                }
            }
        }

        // store D (+modulated bias): row(out)=kg*4+r, col(pixel)=ln15
        #pragma unroll
        for (int c = 0; c < 4; ++c) {
            const int xcol = xstrip + c*16 + ln15;
            #pragma unroll
            for (int ot = 0; ot < 2; ++ot) {
                const int obase = ot*16 + kg*4;
                #pragma unroll
                for (int r = 0; r < 4; ++r) {
                    out[((size_t)(b*COUT + obase + r) * 256 + gy) * 256 + xcol] =
                        acc[c][ot][r] + bm[ot][r];
                }
            }
        }
        __syncthreads();   // ring reads done; drains next-iter async + stores
    }
}

extern "C" void kernel_launch(void* const* d_in, const int* in_sizes, int n_in,
                              void* d_out, int out_size, void* d_ws, size_t ws_size,
                              hipStream_t stream) {
    const float* x       = (const float*)d_in[0];
    const float* cond    = (const float*)d_in[1];
    const float* lpe     = (const float*)d_in[2];
    const float* weights = (const float*)d_in[3];
    const float* bias    = (const float*)d_in[4];
    const float* wa_w    = (const float*)d_in[5];
    const float* wa_b    = (const float*)d_in[6];
    const float* ba_w    = (const float*)d_in[7];
    const float* ba_b    = (const float*)d_in[8];
    float* outp = (float*)d_out;
    float* ws   = (float*)d_ws;    // 1024 floats: wadapt | bias*badapt

    adapt_kernel<<<dim3(B_), dim3(256), 0, stream>>>(
        cond, lpe, wa_w, wa_b, ba_w, ba_b, bias, ws);

    conv_kernel<<<dim3(W_/64, H_/32, B_), dim3(256), 0, stream>>>(
        x, weights, ws, outp);
}